// Round 16
// baseline (70.455 us; speedup 1.0000x reference)
//
#include <hip/hip_runtime.h>

#define T 16
#define E 30
#define H 50
#define VOCAB 100
#define ROWS 208        // 13 row-tiles of 16; rows interleaved r = 4*unit + gate
#define K1 1.44269504089f   // log2(e)
#define K2 2.88539008178f   // 2*log2(e)

typedef _Float16 v8hf __attribute__((ext_vector_type(8)));
typedef float v4f __attribute__((ext_vector_type(4)));

extern "C" __device__ float __ocml_native_exp2_f32(float);
__device__ __forceinline__ float e2(float x)   { return __ocml_native_exp2_f32(x); }
__device__ __forceinline__ float rcpf(float x) { return __builtin_amdgcn_rcpf(x); }

// tbl[dir][v][r], r = 4*unit + gate (i,f,g,o), orig row = gate*50+unit.
// Pre-scaled: i/f/o rows by -log2e, g rows by 2*log2e.
__global__ void build_tbl(const float* __restrict__ emb,
                          const float* __restrict__ w_ih,
                          const float* __restrict__ b_ih,
                          const float* __restrict__ b_hh,
                          float* __restrict__ tbl) {
    int idx = blockIdx.x * blockDim.x + threadIdx.x;
    if (idx >= VOCAB * ROWS) return;
    int v = idx / ROWS, r = idx % ROWS;
    float s = 0.f;
    if (r < 4 * H) {
        int orig = (r & 3) * H + (r >> 2);
        s = b_ih[orig] + b_hh[orig];
        const float* er = emb + v * E;
        const float* wr = w_ih + orig * E;
#pragma unroll
        for (int e = 0; e < E; ++e) s += er[e] * wr[e];
        s *= ((r & 3) == 2) ? K2 : -K1;
    }
    tbl[idx] = s;
}

// M-split: 2 waves share a 16-seq group (tiles 0-6 / 7-12), exchanging h via
// a reader-packed LDS buffer, double-buffered by step parity. Sync = raw
// s_barrier + lgkmcnt(0) only (tv global prefetches stay in flight).
// amdgpu_waves_per_eu(4,4) pins the allocator to the 128-VGPR tier: R8/R11/
// R15 showed launch_bounds(.,4) makes it clamp to 64 VGPR and spill.
template<int RT0, int NT>
__device__ __forceinline__ void run_tiles(
    const float* __restrict__ whh, const float* __restrict__ tb,
    const int* __restrict__ myids, _Float16* __restrict__ hb,
    float* __restrict__ out, int seq, int dir, int capt, int lane)
{
    const int l15 = lane & 15;
    const int lg = lane >> 4;

    // A-fragments (pre-scaled fp16 W) resident for the whole kernel (~56 VGPR)
    v8hf afrag[NT][2];
#pragma unroll
    for (int i = 0; i < NT; ++i) {
        const int r = (RT0 + i) * 16 + l15;
        const bool vr = (r < 4 * H);
        const int orig = vr ? ((r & 3) * H + (r >> 2)) : 0;
        const float sc = ((r & 3) == 2) ? K2 : -K1;
#pragma unroll
        for (int kh = 0; kh < 2; ++kh) {
            v8hf af;
#pragma unroll
            for (int j = 0; j < 8; ++j) {
                const int k = kh * 32 + lg * 8 + j;
                af[j] = (_Float16)((vr && k < H) ? sc * whh[orig * H + k] : 0.f);
            }
            afrag[i][kh] = af;
        }
    }

    // h write offsets (halves): unit u=(RT0+i)*4+lg -> [u>>5][((u&31)>>3)*16+l15][u&7]
    unsigned wa[NT];
#pragma unroll
    for (int i = 0; i < NT; ++i) {
        const int u = (RT0 + i) * 4 + lg;
        wa[i] = ((u >> 5) << 9) + (((u & 31) >> 3) << 7) + (l15 << 3) + (u & 7);
    }

    float cs[NT];
#pragma unroll
    for (int i = 0; i < NT; ++i) cs[i] = 0.f;

    // prefetch tv for t=0
    v4f tv[NT];
    {
        const int id0 = myids[dir ? (T - 1) : 0];
        const float* __restrict__ trow = tb + id0 * ROWS;
#pragma unroll
        for (int i = 0; i < NT; ++i)
            tv[i] = *(const v4f*)(trow + (RT0 + i) * 16 + lg * 4);
    }

#pragma unroll 1
    for (int t = 0; t < T; ++t) {
        const int cur = t & 1, nxt = cur ^ 1;
        int tn = dir ? (T - 2 - t) : (t + 1);
        if (t == T - 1) tn = dir ? 0 : (T - 1);    // dummy valid index
        const int id_next = myids[tn];
        const float* __restrict__ trow_n = tb + id_next * ROWS;

        // full previous-step h: conflict-free contiguous b128 reads
        v8hf bh0 = *(const v8hf*)(hb + cur * 1024 + lane * 8);
        v8hf bh1 = *(const v8hf*)(hb + cur * 1024 + 512 + lane * 8);

        _Float16* wb = hb + nxt * 1024;
        const bool cap = (t == capt);

#pragma unroll
        for (int i = 0; i < NT; ++i) {
            v4f c = __builtin_amdgcn_mfma_f32_16x16x32_f16(afrag[i][0], bh0, tv[i], 0, 0, 0);
            c = __builtin_amdgcn_mfma_f32_16x16x32_f16(afrag[i][1], bh1, c, 0, 0, 0);
            tv[i] = *(const v4f*)(trow_n + (RT0 + i) * 16 + lg * 4);   // prefetch t+1

            // combined-denominator LSTM update: 5 exp2 + 2 rcp per unit
            float ei = e2(c[0]);
            float ef = e2(c[1]);
            float eg = e2(c[2]);
            float eo = e2(c[3]);
            float ai  = 1.f + ei;
            float bf  = 1.f + ef;
            float gp  = eg + 1.f;
            float gm2 = fmaf(K2, eg, -K2);            // K2*(eg-1)
            float num = fmaf(cs[i] * ai, gp, gm2 * bf);
            float rD  = rcpf(ai * bf * gp);
            float cn  = num * rD;                      // cs' = K2 * c_new
            cs[i] = cn;
            float ec  = e2(cn);                        // e^(2 c_new)
            float hn  = (ec - 1.f) * rcpf((1.f + eo) * (ec + 1.f));

            if (RT0 + i < 12 || lg < 2) {              // unit u < 50
                wb[wa[i]] = (_Float16)hn;
                if (cap) out[seq * 100 + dir * H + (RT0 + i) * 4 + lg] = hn;
            }
        }

        // drain LDS only, raw barrier: global prefetches stay in flight
        asm volatile("s_waitcnt lgkmcnt(0)" ::: "memory");
        __builtin_amdgcn_s_barrier();
        asm volatile("" ::: "memory");
    }
}

__global__ __launch_bounds__(256)
__attribute__((amdgpu_waves_per_eu(4, 4)))
void lstm_mfma(
    const int* __restrict__ ids,     // [NSEQ, T]
    const float* __restrict__ tbl,   // [2][VOCAB][ROWS]
    const float* __restrict__ whh_f, // [200][50]
    const float* __restrict__ whh_r, // [200][50]
    float* __restrict__ out)         // [NSEQ, 100]
{
    // [grp][buf][seg][lane][8] fp16 = 8 KB
    __shared__ _Float16 hbuf[2][2][2][64][8];

    const int tid = threadIdx.x;
    const int lane = tid & 63;
    const int wv = tid >> 6;
    const int grp = wv >> 1;         // 2 independent 16-seq groups per block
    const int halfM = wv & 1;        // M-split: tiles 0-6 / 7-12
    const int l15 = lane & 15;
    const int b = blockIdx.x;
    const int dir = b >> 9;          // 1024 blocks: 0..511 fwd, 512..1023 rev
    const int seq = (b & 511) * 32 + grp * 16 + l15;

    const float* __restrict__ whh = dir ? whh_r : whh_f;
    const float* __restrict__ tb  = tbl + dir * (VOCAB * ROWS);
    const int* __restrict__ myids = ids + seq * T;

    // zero all h buffers (4096 halves = 2048 ints; pads stay zero forever)
    {
        int* hz = (int*)&hbuf[0][0][0][0][0];
#pragma unroll
        for (int i = tid; i < 2048; i += 256) hz[i] = 0;
    }

    // ragged length -> capture step (per lane's own sequence)
    int capt;
    {
        const int4* q = (const int4*)myids;
        int4 a0 = q[0], a1 = q[1], a2 = q[2], a3 = q[3];
        int len = (a0.x != 0) + (a0.y != 0) + (a0.z != 0) + (a0.w != 0)
                + (a1.x != 0) + (a1.y != 0) + (a1.z != 0) + (a1.w != 0)
                + (a2.x != 0) + (a2.y != 0) + (a2.z != 0) + (a2.w != 0)
                + (a3.x != 0) + (a3.y != 0) + (a3.z != 0) + (a3.w != 0);
        capt = dir ? (T - 1) : ((len > 1) ? (len - 1) : 0);
    }

    __syncthreads();   // hbuf zeroed (full sync once, pre-loop)

    _Float16* hb = &hbuf[grp][0][0][0][0];
    if (halfM == 0) run_tiles<0, 7>(whh, tb, myids, hb, out, seq, dir, capt, lane);
    else            run_tiles<7, 6>(whh, tb, myids, hb, out, seq, dir, capt, lane);
}

extern "C" void kernel_launch(void* const* d_in, const int* in_sizes, int n_in,
                              void* d_out, int out_size, void* d_ws, size_t ws_size,
                              hipStream_t stream) {
    const int*   char_ids = (const int*)d_in[0];
    const float* emb      = (const float*)d_in[1];
    const float* w_ih_f   = (const float*)d_in[2];
    const float* w_hh_f   = (const float*)d_in[3];
    const float* b_ih_f   = (const float*)d_in[4];
    const float* b_hh_f   = (const float*)d_in[5];
    const float* w_ih_r   = (const float*)d_in[6];
    const float* w_hh_r   = (const float*)d_in[7];
    const float* b_ih_r   = (const float*)d_in[8];
    const float* b_hh_r   = (const float*)d_in[9];
    float* out = (float*)d_out;
    float* tbl = (float*)d_ws; // [2][VOCAB][ROWS] f32 = 166.4 KB

    const int nt = VOCAB * ROWS; // 20800
    build_tbl<<<(nt + 255) / 256, 256, 0, stream>>>(emb, w_ih_f, b_ih_f, b_hh_f, tbl);
    build_tbl<<<(nt + 255) / 256, 256, 0, stream>>>(emb, w_ih_r, b_ih_r, b_hh_r, tbl + nt);
    // 1024 blocks x 256: 2 seq-groups x 2 M-split waves -> 4096 waves (4/SIMD)
    lstm_mfma<<<1024, 256, 0, stream>>>(char_ids, tbl, w_hh_f, w_hh_r, out);
}

// Round 17
// 64.332 us; speedup vs baseline: 1.0952x; 1.0952x over previous
//
#include <hip/hip_runtime.h>

#define T 16
#define E 30
#define H 50
#define VOCAB 100
#define ROWS 208        // 13 row-tiles of 16; rows interleaved r = 4*unit + gate
#define K1 1.44269504089f   // log2(e)
#define K2 2.88539008178f   // 2*log2(e)

typedef _Float16 v8hf __attribute__((ext_vector_type(8)));
typedef _Float16 v4hf __attribute__((ext_vector_type(4)));
typedef float v4f __attribute__((ext_vector_type(4)));

extern "C" __device__ float __ocml_native_exp2_f32(float);
__device__ __forceinline__ float e2(float x)   { return __ocml_native_exp2_f32(x); }
__device__ __forceinline__ float rcpf(float x) { return __builtin_amdgcn_rcpf(x); }

// fp16 tbl[dir][v][r], r = 4*unit + gate (i,f,g,o), orig row = gate*50+unit.
// Pre-scaled: i/f/o rows by -log2e, g rows by 2*log2e. fp16 quantization of
// the pre-activations verified harmless in R14 (absmax unchanged).
__global__ void build_tbl(const float* __restrict__ emb,
                          const float* __restrict__ w_ih,
                          const float* __restrict__ b_ih,
                          const float* __restrict__ b_hh,
                          _Float16* __restrict__ tbl) {
    int idx = blockIdx.x * blockDim.x + threadIdx.x;
    if (idx >= VOCAB * ROWS) return;
    int v = idx / ROWS, r = idx % ROWS;
    float s = 0.f;
    if (r < 4 * H) {
        int orig = (r & 3) * H + (r >> 2);
        s = b_ih[orig] + b_hh[orig];
        const float* er = emb + v * E;
        const float* wr = w_ih + orig * E;
#pragma unroll
        for (int e = 0; e < E; ++e) s += er[e] * wr[e];
        s *= ((r & 3) == 2) ? K2 : -K1;
    }
    tbl[idx] = (_Float16)s;
}

// M-split: 2 waves share a 16-seq group (tiles 0-6 / 7-12), h via reader-
// packed LDS, double-buffered by parity. Sync = raw s_barrier + lgkmcnt(0).
// fp16 tv prefetch (14 VGPR, not 28) so total regs (arch+AGPR) fit the
// 128/wave budget of the 4-waves/SIMD tier — R15/16 missed it by ~10.
template<int RT0, int NT>
__device__ __forceinline__ void run_tiles(
    const float* __restrict__ whh, const _Float16* __restrict__ tb,
    const int* __restrict__ myids, _Float16* __restrict__ hb,
    float* __restrict__ out, int seq, int dir, int capt, int lane)
{
    const int l15 = lane & 15;
    const int lg = lane >> 4;

    // A-fragments (pre-scaled fp16 W), resident in AGPRs for the kernel
    v8hf afrag[NT][2];
#pragma unroll
    for (int i = 0; i < NT; ++i) {
        const int r = (RT0 + i) * 16 + l15;
        const bool vr = (r < 4 * H);
        const int orig = vr ? ((r & 3) * H + (r >> 2)) : 0;
        const float sc = ((r & 3) == 2) ? K2 : -K1;
#pragma unroll
        for (int kh = 0; kh < 2; ++kh) {
            v8hf af;
#pragma unroll
            for (int j = 0; j < 8; ++j) {
                const int k = kh * 32 + lg * 8 + j;
                af[j] = (_Float16)((vr && k < H) ? sc * whh[orig * H + k] : 0.f);
            }
            afrag[i][kh] = af;
        }
    }

    float cs[NT];
#pragma unroll
    for (int i = 0; i < NT; ++i) cs[i] = 0.f;

    // prefetch tv (fp16) for t=0
    v4hf tv[NT];
    {
        const int id0 = myids[dir ? (T - 1) : 0];
        const _Float16* __restrict__ trow = tb + id0 * ROWS + lg * 4;
#pragma unroll
        for (int i = 0; i < NT; ++i)
            tv[i] = *(const v4hf*)(trow + (RT0 + i) * 16);
    }

#pragma unroll 1
    for (int t = 0; t < T; ++t) {
        const int cur = t & 1, nxt = cur ^ 1;
        int tn = dir ? (T - 2 - t) : (t + 1);
        if (t == T - 1) tn = dir ? 0 : (T - 1);    // dummy valid index
        const int id_next = myids[tn];
        const _Float16* __restrict__ trow_n = tb + id_next * ROWS + lg * 4;

        // full previous-step h: conflict-free contiguous b128 reads
        v8hf bh0 = *(const v8hf*)(hb + cur * 1024 + lane * 8);
        v8hf bh1 = *(const v8hf*)(hb + cur * 1024 + 512 + lane * 8);

        _Float16* wb = hb + nxt * 1024;
        const bool cap = (t == capt);

#pragma unroll
        for (int i = 0; i < NT; ++i) {
            v4f tvv;
            tvv[0] = (float)tv[i][0]; tvv[1] = (float)tv[i][1];
            tvv[2] = (float)tv[i][2]; tvv[3] = (float)tv[i][3];
            v4f c = __builtin_amdgcn_mfma_f32_16x16x32_f16(afrag[i][0], bh0, tvv, 0, 0, 0);
            c = __builtin_amdgcn_mfma_f32_16x16x32_f16(afrag[i][1], bh1, c, 0, 0, 0);
            tv[i] = *(const v4hf*)(trow_n + (RT0 + i) * 16);   // prefetch t+1

            // combined-denominator LSTM update: 5 exp2 + 2 rcp per unit
            float ei = e2(c[0]);
            float ef = e2(c[1]);
            float eg = e2(c[2]);
            float eo = e2(c[3]);
            float ai  = 1.f + ei;
            float bf  = 1.f + ef;
            float gp  = eg + 1.f;
            float gm2 = fmaf(K2, eg, -K2);            // K2*(eg-1)
            float num = fmaf(cs[i] * ai, gp, gm2 * bf);
            float rD  = rcpf(ai * bf * gp);
            float cn  = num * rD;                      // cs' = K2 * c_new
            cs[i] = cn;
            float ec  = e2(cn);                        // e^(2 c_new)
            float hn  = (ec - 1.f) * rcpf((1.f + eo) * (ec + 1.f));

            if (RT0 + i < 12 || lg < 2) {              // unit u < 50
                const int u = (RT0 + i) * 4 + lg;
                const unsigned wa = ((u >> 5) << 9) + (((u & 31) >> 3) << 7)
                                  + (l15 << 3) + (u & 7);
                wb[wa] = (_Float16)hn;
                if (cap) out[seq * 100 + dir * H + u] = hn;
            }
        }

        // drain LDS only, raw barrier: global prefetches stay in flight
        asm volatile("s_waitcnt lgkmcnt(0)" ::: "memory");
        __builtin_amdgcn_s_barrier();
        asm volatile("" ::: "memory");
    }
}

__global__ __launch_bounds__(256)
__attribute__((amdgpu_waves_per_eu(4, 4)))
void lstm_mfma(
    const int* __restrict__ ids,       // [NSEQ, T]
    const _Float16* __restrict__ tbl,  // [2][VOCAB][ROWS] fp16
    const float* __restrict__ whh_f,   // [200][50]
    const float* __restrict__ whh_r,   // [200][50]
    float* __restrict__ out)           // [NSEQ, 100]
{
    // [grp][buf][seg][lane][8] fp16 = 8 KB
    __shared__ _Float16 hbuf[2][2][2][64][8];

    const int tid = threadIdx.x;
    const int lane = tid & 63;
    const int wv = tid >> 6;
    const int grp = wv >> 1;         // 2 independent 16-seq groups per block
    const int halfM = wv & 1;        // M-split: tiles 0-6 / 7-12
    const int l15 = lane & 15;
    const int b = blockIdx.x;
    const int dir = b >> 9;          // 1024 blocks: 0..511 fwd, 512..1023 rev
    const int seq = (b & 511) * 32 + grp * 16 + l15;

    const float* __restrict__ whh = dir ? whh_r : whh_f;
    const _Float16* __restrict__ tb = tbl + dir * (VOCAB * ROWS);
    const int* __restrict__ myids = ids + seq * T;

    // zero all h buffers (4096 halves = 2048 ints; pads stay zero forever)
    {
        int* hz = (int*)&hbuf[0][0][0][0][0];
#pragma unroll
        for (int i = tid; i < 2048; i += 256) hz[i] = 0;
    }

    // ragged length -> capture step (per lane's own sequence)
    int capt;
    {
        const int4* q = (const int4*)myids;
        int4 a0 = q[0], a1 = q[1], a2 = q[2], a3 = q[3];
        int len = (a0.x != 0) + (a0.y != 0) + (a0.z != 0) + (a0.w != 0)
                + (a1.x != 0) + (a1.y != 0) + (a1.z != 0) + (a1.w != 0)
                + (a2.x != 0) + (a2.y != 0) + (a2.z != 0) + (a2.w != 0)
                + (a3.x != 0) + (a3.y != 0) + (a3.z != 0) + (a3.w != 0);
        capt = dir ? (T - 1) : ((len > 1) ? (len - 1) : 0);
    }

    __syncthreads();   // hbuf zeroed (full sync once, pre-loop)

    _Float16* hb = &hbuf[grp][0][0][0][0];
    if (halfM == 0) run_tiles<0, 7>(whh, tb, myids, hb, out, seq, dir, capt, lane);
    else            run_tiles<7, 6>(whh, tb, myids, hb, out, seq, dir, capt, lane);
}

extern "C" void kernel_launch(void* const* d_in, const int* in_sizes, int n_in,
                              void* d_out, int out_size, void* d_ws, size_t ws_size,
                              hipStream_t stream) {
    const int*   char_ids = (const int*)d_in[0];
    const float* emb      = (const float*)d_in[1];
    const float* w_ih_f   = (const float*)d_in[2];
    const float* w_hh_f   = (const float*)d_in[3];
    const float* b_ih_f   = (const float*)d_in[4];
    const float* b_hh_f   = (const float*)d_in[5];
    const float* w_ih_r   = (const float*)d_in[6];
    const float* w_hh_r   = (const float*)d_in[7];
    const float* b_ih_r   = (const float*)d_in[8];
    const float* b_hh_r   = (const float*)d_in[9];
    float* out = (float*)d_out;
    _Float16* tbl = (_Float16*)d_ws; // [2][VOCAB][ROWS] fp16 = 83.2 KB

    const int nt = VOCAB * ROWS; // 20800
    build_tbl<<<(nt + 255) / 256, 256, 0, stream>>>(emb, w_ih_f, b_ih_f, b_hh_f, tbl);
    build_tbl<<<(nt + 255) / 256, 256, 0, stream>>>(emb, w_ih_r, b_ih_r, b_hh_r, tbl + nt);
    // 1024 blocks x 256: 2 seq-groups x 2 M-split waves -> 4096 waves (4/SIMD)
    lstm_mfma<<<1024, 256, 0, stream>>>(char_ids, tbl, w_hh_f, w_hh_r, out);
}

// Round 18
// 61.920 us; speedup vs baseline: 1.1378x; 1.0390x over previous
//
#include <hip/hip_runtime.h>

#define T 16
#define E 30
#define H 50
#define VOCAB 100
#define ROWS 208        // 13 row-tiles of 16; rows interleaved r = 4*unit + gate
#define K1 1.44269504089f   // log2(e)
#define K2 2.88539008178f   // 2*log2(e)

typedef _Float16 v8hf __attribute__((ext_vector_type(8)));
typedef _Float16 v4hf __attribute__((ext_vector_type(4)));
typedef float v4f __attribute__((ext_vector_type(4)));

extern "C" __device__ float __ocml_native_exp2_f32(float);
__device__ __forceinline__ float e2(float x)   { return __ocml_native_exp2_f32(x); }
__device__ __forceinline__ float rcpf(float x) { return __builtin_amdgcn_rcpf(x); }

// ONE launch builds both directions' fp16 tables (saves a launch + gap).
// tbl[dir][v][r], r = 4*unit + gate (i,f,g,o), orig row = gate*50+unit.
// Pre-scaled: i/f/o rows by -log2e, g rows by 2*log2e.
__global__ void build_tbl2(const float* __restrict__ emb,
                           const float* __restrict__ w_ih_f,
                           const float* __restrict__ b_ih_f,
                           const float* __restrict__ b_hh_f,
                           const float* __restrict__ w_ih_r,
                           const float* __restrict__ b_ih_r,
                           const float* __restrict__ b_hh_r,
                           _Float16* __restrict__ tbl) {
    int gidx = blockIdx.x * blockDim.x + threadIdx.x;
    if (gidx >= 2 * VOCAB * ROWS) return;
    const int d = gidx / (VOCAB * ROWS);
    const int idx = gidx - d * (VOCAB * ROWS);
    const float* __restrict__ w_ih = d ? w_ih_r : w_ih_f;
    const float* __restrict__ b_ih = d ? b_ih_r : b_ih_f;
    const float* __restrict__ b_hh = d ? b_hh_r : b_hh_f;
    int v = idx / ROWS, r = idx % ROWS;
    float s = 0.f;
    if (r < 4 * H) {
        int orig = (r & 3) * H + (r >> 2);
        s = b_ih[orig] + b_hh[orig];
        const float* er = emb + v * E;
        const float* wr = w_ih + orig * E;
#pragma unroll
        for (int e = 0; e < E; ++e) s += er[e] * wr[e];
        s *= ((r & 3) == 2) ? K2 : -K1;
    }
    tbl[gidx] = (_Float16)s;
}

// M-split: 2 waves share a 16-seq group (tiles 0-6 / 7-12), h via reader-
// packed LDS, double-buffered by parity. Sync = raw s_barrier + lgkmcnt(0)
// (tv global prefetches stay in flight across it). fp16 tv keeps the total
// register footprint (arch+AGPR ~120) inside the 128/wave 4-waves/SIMD tier.
template<int RT0, int NT>
__device__ __forceinline__ void run_tiles(
    const float* __restrict__ whh, const _Float16* __restrict__ tb,
    const int* __restrict__ myids, _Float16* __restrict__ hb,
    float* __restrict__ out, int seq, int dir, int capt, int lane)
{
    const int l15 = lane & 15;
    const int lg = lane >> 4;

    // A-fragments (pre-scaled fp16 W), resident in AGPRs for the kernel
    v8hf afrag[NT][2];
#pragma unroll
    for (int i = 0; i < NT; ++i) {
        const int r = (RT0 + i) * 16 + l15;
        const bool vr = (r < 4 * H);
        const int orig = vr ? ((r & 3) * H + (r >> 2)) : 0;
        const float sc = ((r & 3) == 2) ? K2 : -K1;
#pragma unroll
        for (int kh = 0; kh < 2; ++kh) {
            v8hf af;
#pragma unroll
            for (int j = 0; j < 8; ++j) {
                const int k = kh * 32 + lg * 8 + j;
                af[j] = (_Float16)((vr && k < H) ? sc * whh[orig * H + k] : 0.f);
            }
            afrag[i][kh] = af;
        }
    }

    float cs[NT];
#pragma unroll
    for (int i = 0; i < NT; ++i) cs[i] = 0.f;

    // prefetch tv (fp16) for t=0
    v4hf tv[NT];
    {
        const int id0 = myids[dir ? (T - 1) : 0];
        const _Float16* __restrict__ trow = tb + id0 * ROWS + lg * 4;
#pragma unroll
        for (int i = 0; i < NT; ++i)
            tv[i] = *(const v4hf*)(trow + (RT0 + i) * 16);
    }

#pragma unroll 1
    for (int t = 0; t < T; ++t) {
        const int cur = t & 1, nxt = cur ^ 1;
        int tn = dir ? (T - 2 - t) : (t + 1);
        if (t == T - 1) tn = dir ? 0 : (T - 1);    // dummy valid index
        const int id_next = myids[tn];
        const _Float16* __restrict__ trow_n = tb + id_next * ROWS + lg * 4;

        // full previous-step h: conflict-free contiguous b128 reads
        v8hf bh0 = *(const v8hf*)(hb + cur * 1024 + lane * 8);
        v8hf bh1 = *(const v8hf*)(hb + cur * 1024 + 512 + lane * 8);

        _Float16* wb = hb + nxt * 1024;
        const bool cap = (t == capt);

#pragma unroll
        for (int i = 0; i < NT; ++i) {
            v4f tvv;
            tvv[0] = (float)tv[i][0]; tvv[1] = (float)tv[i][1];
            tvv[2] = (float)tv[i][2]; tvv[3] = (float)tv[i][3];
            v4f c = __builtin_amdgcn_mfma_f32_16x16x32_f16(afrag[i][0], bh0, tvv, 0, 0, 0);
            c = __builtin_amdgcn_mfma_f32_16x16x32_f16(afrag[i][1], bh1, c, 0, 0, 0);
            tv[i] = *(const v4hf*)(trow_n + (RT0 + i) * 16);   // prefetch t+1

            // combined-denominator LSTM update: 5 exp2 + 2 rcp per unit
            float ei = e2(c[0]);
            float ef = e2(c[1]);
            float eg = e2(c[2]);
            float eo = e2(c[3]);
            float ai  = 1.f + ei;
            float bf  = 1.f + ef;
            float gp  = eg + 1.f;
            float gm2 = fmaf(K2, eg, -K2);            // K2*(eg-1)
            float num = fmaf(cs[i] * ai, gp, gm2 * bf);
            float rD  = rcpf(ai * bf * gp);
            float cn  = num * rD;                      // cs' = K2 * c_new
            cs[i] = cn;
            float ec  = e2(cn);                        // e^(2 c_new)
            float hn  = (ec - 1.f) * rcpf((1.f + eo) * (ec + 1.f));

            if (RT0 + i < 12 || lg < 2) {              // unit u < 50
                const int u = (RT0 + i) * 4 + lg;
                const unsigned wa = ((u >> 5) << 9) + (((u & 31) >> 3) << 7)
                                  + (l15 << 3) + (u & 7);
                wb[wa] = (_Float16)hn;
                if (cap) out[seq * 100 + dir * H + u] = hn;
            }
        }

        // drain LDS only, raw barrier: global prefetches stay in flight
        asm volatile("s_waitcnt lgkmcnt(0)" ::: "memory");
        __builtin_amdgcn_s_barrier();
        asm volatile("" ::: "memory");
    }
}

__global__ __launch_bounds__(256)
__attribute__((amdgpu_waves_per_eu(4, 4)))
void lstm_mfma(
    const int* __restrict__ ids,       // [NSEQ, T]
    const _Float16* __restrict__ tbl,  // [2][VOCAB][ROWS] fp16
    const float* __restrict__ whh_f,   // [200][50]
    const float* __restrict__ whh_r,   // [200][50]
    float* __restrict__ out)           // [NSEQ, 100]
{
    // [grp][buf][seg][lane][8] fp16 = 8 KB
    __shared__ _Float16 hbuf[2][2][2][64][8];

    const int tid = threadIdx.x;
    const int lane = tid & 63;
    const int wv = tid >> 6;
    const int grp = wv >> 1;         // 2 independent 16-seq groups per block
    const int halfM = wv & 1;        // M-split: tiles 0-6 / 7-12
    const int l15 = lane & 15;
    const int b = blockIdx.x;
    const int dir = b >> 9;          // 1024 blocks: 0..511 fwd, 512..1023 rev
    const int seq = (b & 511) * 32 + grp * 16 + l15;

    const float* __restrict__ whh = dir ? whh_r : whh_f;
    const _Float16* __restrict__ tb = tbl + dir * (VOCAB * ROWS);
    const int* __restrict__ myids = ids + seq * T;

    // zero all h buffers (4096 halves = 2048 ints; pads stay zero forever)
    {
        int* hz = (int*)&hbuf[0][0][0][0][0];
#pragma unroll
        for (int i = tid; i < 2048; i += 256) hz[i] = 0;
    }

    // ragged length -> capture step (per lane's own sequence)
    int capt;
    {
        const int4* q = (const int4*)myids;
        int4 a0 = q[0], a1 = q[1], a2 = q[2], a3 = q[3];
        int len = (a0.x != 0) + (a0.y != 0) + (a0.z != 0) + (a0.w != 0)
                + (a1.x != 0) + (a1.y != 0) + (a1.z != 0) + (a1.w != 0)
                + (a2.x != 0) + (a2.y != 0) + (a2.z != 0) + (a2.w != 0)
                + (a3.x != 0) + (a3.y != 0) + (a3.z != 0) + (a3.w != 0);
        capt = dir ? (T - 1) : ((len > 1) ? (len - 1) : 0);
    }

    __syncthreads();   // hbuf zeroed (full sync once, pre-loop)

    _Float16* hb = &hbuf[grp][0][0][0][0];
    if (halfM == 0) run_tiles<0, 7>(whh, tb, myids, hb, out, seq, dir, capt, lane);
    else            run_tiles<7, 6>(whh, tb, myids, hb, out, seq, dir, capt, lane);
}

extern "C" void kernel_launch(void* const* d_in, const int* in_sizes, int n_in,
                              void* d_out, int out_size, void* d_ws, size_t ws_size,
                              hipStream_t stream) {
    const int*   char_ids = (const int*)d_in[0];
    const float* emb      = (const float*)d_in[1];
    const float* w_ih_f   = (const float*)d_in[2];
    const float* w_hh_f   = (const float*)d_in[3];
    const float* b_ih_f   = (const float*)d_in[4];
    const float* b_hh_f   = (const float*)d_in[5];
    const float* w_ih_r   = (const float*)d_in[6];
    const float* w_hh_r   = (const float*)d_in[7];
    const float* b_ih_r   = (const float*)d_in[8];
    const float* b_hh_r   = (const float*)d_in[9];
    float* out = (float*)d_out;
    _Float16* tbl = (_Float16*)d_ws; // [2][VOCAB][ROWS] fp16 = 83.2 KB

    const int nt2 = 2 * VOCAB * ROWS; // 41600 (both directions, one launch)
    build_tbl2<<<(nt2 + 255) / 256, 256, 0, stream>>>(
        emb, w_ih_f, b_ih_f, b_hh_f, w_ih_r, b_ih_r, b_hh_r, tbl);
    // 1024 blocks x 256: 2 seq-groups x 2 M-split waves -> 4096 waves (4/SIMD)
    lstm_mfma<<<1024, 256, 0, stream>>>(char_ids, tbl, w_hh_f, w_hh_r, out);
}